// Round 1
// baseline (1436.981 us; speedup 1.0000x reference)
//
#include <hip/hip_runtime.h>

#define NG 1024

// ---------------- init: deg=1 (self-loop), zero pooled sums/counts ----------
__global__ void k_init(float* __restrict__ deg, float* __restrict__ pooled,
                       float* __restrict__ cnt, int N) {
    int i = blockIdx.x * blockDim.x + threadIdx.x;
    if (i < N) deg[i] = 1.0f;
    if (i < NG * 32) pooled[i] = 0.0f;
    if (i < NG) cnt[i] = 0.0f;
}

// ---------------- degree histogram over dst ---------------------------------
__global__ void k_deg(const int* __restrict__ dst, float* __restrict__ deg, int E) {
    int e = blockIdx.x * blockDim.x + threadIdx.x;
    if (e < E) atomicAdd(&deg[dst[e]], 1.0f);
}

// ---------------- deg -> d^-1/2 in place ------------------------------------
__global__ void k_dinv(float* __restrict__ deg, int N) {
    int v = blockIdx.x * blockDim.x + threadIdx.x;
    if (v < N) deg[v] = rsqrtf(deg[v]);   // deg >= 1 (self-loop) so no zero case
}

// ---------------- layer-1 node transform: hs1 = dinv * (x @ W1) -------------
__global__ void k_l1node(const float* __restrict__ x, const float* __restrict__ W1,
                         const float* __restrict__ dinv, float* __restrict__ hs1,
                         float* __restrict__ acc1, int N) {
    __shared__ float sW[48];
    if (threadIdx.x < 48) sW[threadIdx.x] = W1[threadIdx.x];
    __syncthreads();
    int v = blockIdx.x * blockDim.x + threadIdx.x;
    if (v >= N) return;
    float x0 = x[v * 3 + 0], x1 = x[v * 3 + 1], x2 = x[v * 3 + 2];
    float d = dinv[v];
#pragma unroll
    for (int f = 0; f < 16; ++f) {
        float h = d * (x0 * sW[f] + x1 * sW[16 + f] + x2 * sW[32 + f]);
        hs1[v * 16 + f] = h;
        acc1[v * 16 + f] = h;              // self-loop contribution
    }
}

// ---------------- edge scatter: acc[dst] += hs[src], F floats/edge ----------
template <int F>
__global__ void k_edge(const int* __restrict__ src, const int* __restrict__ dst,
                       const float* __restrict__ hs, float* __restrict__ acc, int E) {
    int t = blockIdx.x * blockDim.x + threadIdx.x;
    int e = t / F;              // F is a power of two -> shifts
    int f = t % F;
    if (e >= E) return;
    int s = src[e], d0 = dst[e];
    atomicAdd(&acc[d0 * F + f], hs[s * F + f]);
}

// ------- finish layer 1 (scale, +b1, relu) and node transform for layer 2 ---
__global__ void k_mid(const float* __restrict__ acc1, const float* __restrict__ b1,
                      const float* __restrict__ W2, const float* __restrict__ dinv,
                      float* __restrict__ hs2, float* __restrict__ acc2, int N) {
    __shared__ float sW[16 * 32];
    __shared__ float sb1[16];
    for (int i = threadIdx.x; i < 512; i += blockDim.x) sW[i] = W2[i];
    if (threadIdx.x < 16) sb1[threadIdx.x] = b1[threadIdx.x];
    __syncthreads();
    int v = blockIdx.x * blockDim.x + threadIdx.x;
    if (v >= N) return;
    float d = dinv[v];
    float h1[16];
#pragma unroll
    for (int k = 0; k < 16; ++k)
        h1[k] = fmaxf(d * acc1[v * 16 + k] + sb1[k], 0.0f);
#pragma unroll
    for (int f = 0; f < 32; ++f) {
        float s = 0.0f;
#pragma unroll
        for (int k = 0; k < 16; ++k) s += h1[k] * sW[k * 32 + f];
        s *= d;
        hs2[v * 32 + f] = s;
        acc2[v * 32 + f] = s;              // self-loop contribution
    }
}

// ------- finish layer 2 + atomic mean-pool accumulation ---------------------
__global__ void k_pool(const float* __restrict__ acc2, const float* __restrict__ b2,
                       const float* __restrict__ dinv, const int* __restrict__ batch,
                       float* __restrict__ pooled, float* __restrict__ cnt, int N) {
    int t = blockIdx.x * blockDim.x + threadIdx.x;
    int v = t >> 5, f = t & 31;
    if (v >= N) return;
    float h = fmaxf(dinv[v] * acc2[v * 32 + f] + b2[f], 0.0f);
    int g = batch[v];
    atomicAdd(&pooled[g * 32 + f], h);
    if (f == 0) atomicAdd(&cnt[g], 1.0f);
}

// ------- final linear head: out[g] = (pooled[g]/cnt[g]) @ Wl + bl -----------
__global__ void k_out(const float* __restrict__ pooled, const float* __restrict__ cnt,
                      const float* __restrict__ Wl, const float* __restrict__ bl,
                      float* __restrict__ out) {
    int t = blockIdx.x * blockDim.x + threadIdx.x;
    if (t >= NG * 3) return;
    int g = t / 3, c = t % 3;
    float inv = 1.0f / fmaxf(cnt[g], 1.0f);
    float s = bl[c];
#pragma unroll
    for (int f = 0; f < 32; ++f) s += pooled[g * 32 + f] * inv * Wl[f * 3 + c];
    out[g * 3 + c] = s;
}

extern "C" void kernel_launch(void* const* d_in, const int* in_sizes, int n_in,
                              void* d_out, int out_size, void* d_ws, size_t ws_size,
                              hipStream_t stream) {
    const float* x     = (const float*)d_in[0];
    const int*   ei    = (const int*)d_in[1];
    const int*   batch = (const int*)d_in[2];
    const float* W1    = (const float*)d_in[3];
    const float* b1    = (const float*)d_in[4];
    const float* W2    = (const float*)d_in[5];
    const float* b2    = (const float*)d_in[6];
    const float* Wl    = (const float*)d_in[7];
    const float* bl    = (const float*)d_in[8];

    const int N = in_sizes[0] / 3;
    const int E = in_sizes[1] / 2;
    const int* src = ei;
    const int* dst = ei + E;

    float* ws     = (float*)d_ws;
    float* deg    = ws;                          // N floats (becomes dinv in place)
    float* hs1    = deg  + (size_t)N;            // N*16
    float* acc1   = hs1  + (size_t)N * 16;       // N*16
    float* hs2    = acc1 + (size_t)N * 16;       // N*32
    float* acc2   = hs2  + (size_t)N * 32;       // N*32
    float* pooled = acc2 + (size_t)N * 32;       // NG*32
    float* cnt    = pooled + (size_t)NG * 32;    // NG

    const int B = 256;
    const int gN = (N + B - 1) / B;

    k_init<<<gN, B, 0, stream>>>(deg, pooled, cnt, N);
    k_deg<<<(E + B - 1) / B, B, 0, stream>>>(dst, deg, E);
    k_dinv<<<gN, B, 0, stream>>>(deg, N);
    k_l1node<<<gN, B, 0, stream>>>(x, W1, deg, hs1, acc1, N);

    long long t1 = (long long)E * 16;
    k_edge<16><<<(int)((t1 + B - 1) / B), B, 0, stream>>>(src, dst, hs1, acc1, E);

    k_mid<<<gN, B, 0, stream>>>(acc1, b1, W2, deg, hs2, acc2, N);

    long long t2 = (long long)E * 32;
    k_edge<32><<<(int)((t2 + B - 1) / B), B, 0, stream>>>(src, dst, hs2, acc2, E);

    long long tp = (long long)N * 32;
    k_pool<<<(int)((tp + B - 1) / B), B, 0, stream>>>(acc2, b2, deg, batch, pooled, cnt, N);

    k_out<<<(NG * 3 + B - 1) / B, B, 0, stream>>>(pooled, cnt, Wl, bl, (float*)d_out);
}

// Round 2
// 1090.548 us; speedup vs baseline: 1.3177x; 1.3177x over previous
//
#include <hip/hip_runtime.h>

#define NG 1024
#define SCAN_B 1024

// ---------------- zero: degi (cursor), pooled, cnt --------------------------
__global__ void k_zero(int* __restrict__ degi, float* __restrict__ pooled,
                       float* __restrict__ cnt, int N) {
    int i = blockIdx.x * blockDim.x + threadIdx.x;
    if (i < N) degi[i] = 0;
    if (i < NG * 32) pooled[i] = 0.0f;
    if (i < NG) cnt[i] = 0.0f;
}

// ---------------- degree histogram over dst (int atomics) -------------------
__global__ void k_deg(const int* __restrict__ dst, int* __restrict__ degi, int E) {
    int e = blockIdx.x * blockDim.x + threadIdx.x;
    if (e < E) atomicAdd(&degi[dst[e]], 1);
}

// ---------------- scan stage A: per-block inclusive scan --------------------
__global__ void k_scanA(const int* __restrict__ degi, int* __restrict__ tmp,
                        int* __restrict__ part, int N) {
    __shared__ int s[SCAN_B];
    int gid = blockIdx.x * SCAN_B + threadIdx.x;
    s[threadIdx.x] = (gid < N) ? degi[gid] : 0;
    __syncthreads();
    for (int off = 1; off < SCAN_B; off <<= 1) {
        int t = (threadIdx.x >= off) ? s[threadIdx.x - off] : 0;
        __syncthreads();
        s[threadIdx.x] += t;
        __syncthreads();
    }
    if (gid < N) tmp[gid] = s[threadIdx.x];
    if (threadIdx.x == SCAN_B - 1) part[blockIdx.x] = s[SCAN_B - 1];
}

// ---------------- scan stage B: scan of block partials (single block) -------
__global__ void k_scanB(int* __restrict__ part, int NB) {
    __shared__ int s[SCAN_B];
    int v = (threadIdx.x < NB) ? part[threadIdx.x] : 0;
    s[threadIdx.x] = v;
    __syncthreads();
    for (int off = 1; off < SCAN_B; off <<= 1) {
        int t = (threadIdx.x >= off) ? s[threadIdx.x - off] : 0;
        __syncthreads();
        s[threadIdx.x] += t;
        __syncthreads();
    }
    // exclusive result
    if (threadIdx.x < NB) part[threadIdx.x] = threadIdx.x ? s[threadIdx.x - 1] : 0;
}

// ------- scan stage C: row_ptr = exclusive scan; dinv; clear degi (cursor) --
__global__ void k_scanC(const int* __restrict__ tmp, const int* __restrict__ part,
                        int* __restrict__ row_ptr, int* __restrict__ degi,
                        float* __restrict__ dinv, int N) {
    int i = blockIdx.x * blockDim.x + threadIdx.x;
    if (i >= N) return;
    row_ptr[i + 1] = tmp[i] + part[i >> 10];   // SCAN_B = 1024
    if (i == 0) row_ptr[0] = 0;
    dinv[i] = rsqrtf((float)degi[i] + 1.0f);   // +1 self-loop
    degi[i] = 0;                               // becomes fill cursor
}

// ---------------- CSR fill: counting-sort edges by dst ----------------------
__global__ void k_fill(const int* __restrict__ src, const int* __restrict__ dst,
                       const int* __restrict__ row_ptr, int* __restrict__ cursor,
                       int* __restrict__ csr, int E) {
    int e = blockIdx.x * blockDim.x + threadIdx.x;
    if (e >= E) return;
    int d = dst[e];
    int pos = atomicAdd(&cursor[d], 1);
    csr[row_ptr[d] + pos] = src[e];
}

// ---------------- layer-1 node transform: hs1 = dinv * (x @ W1) -------------
__global__ void k_l1node(const float* __restrict__ x, const float* __restrict__ W1,
                         const float* __restrict__ dinv, float* __restrict__ hs1, int N) {
    __shared__ float sW[48];
    if (threadIdx.x < 48) sW[threadIdx.x] = W1[threadIdx.x];
    __syncthreads();
    int v = blockIdx.x * blockDim.x + threadIdx.x;
    if (v >= N) return;
    float x0 = x[v * 3 + 0], x1 = x[v * 3 + 1], x2 = x[v * 3 + 2];
    float d = dinv[v];
#pragma unroll
    for (int f = 0; f < 16; ++f)
        hs1[v * 16 + f] = d * (x0 * sW[f] + x1 * sW[16 + f] + x2 * sW[32 + f]);
}

// ------- gather layer 1: h1 = relu(dinv * (self + sum_in hs1[src]) + b1) ----
// 4 lanes per node, float4 each (F=16)
__global__ void k_gather16(const int* __restrict__ row_ptr, const int* __restrict__ csr,
                           const float* __restrict__ hs1, const float* __restrict__ dinv,
                           const float* __restrict__ b1, float* __restrict__ h1, int N) {
    int t = blockIdx.x * blockDim.x + threadIdx.x;
    int v = t >> 2, q = t & 3;
    if (v >= N) return;
    const float4* hs4 = (const float4*)hs1;
    float4 sum = hs4[v * 4 + q];               // self-loop
    int beg = row_ptr[v], end = row_ptr[v + 1];
    for (int i = beg; i < end; ++i) {
        int s = csr[i];
        float4 a = hs4[s * 4 + q];
        sum.x += a.x; sum.y += a.y; sum.z += a.z; sum.w += a.w;
    }
    float d = dinv[v];
    float4 b = ((const float4*)b1)[q];
    float4 h;
    h.x = fmaxf(d * sum.x + b.x, 0.0f);
    h.y = fmaxf(d * sum.y + b.y, 0.0f);
    h.z = fmaxf(d * sum.z + b.z, 0.0f);
    h.w = fmaxf(d * sum.w + b.w, 0.0f);
    ((float4*)h1)[v * 4 + q] = h;
}

// ------- layer-2 node transform: hs2 = dinv * (h1 @ W2) ---------------------
__global__ void k_mid2(const float* __restrict__ h1, const float* __restrict__ W2,
                       const float* __restrict__ dinv, float* __restrict__ hs2, int N) {
    __shared__ float sW[16 * 32];
    for (int i = threadIdx.x; i < 512; i += blockDim.x) sW[i] = W2[i];
    __syncthreads();
    int v = blockIdx.x * blockDim.x + threadIdx.x;
    if (v >= N) return;
    float d = dinv[v];
    float a[16];
#pragma unroll
    for (int k = 0; k < 16; ++k) a[k] = h1[v * 16 + k];
#pragma unroll
    for (int f = 0; f < 32; ++f) {
        float s = 0.0f;
#pragma unroll
        for (int k = 0; k < 16; ++k) s += a[k] * sW[k * 32 + f];
        hs2[v * 32 + f] = d * s;
    }
}

// ------- gather layer 2 + fused mean-pool accumulation ----------------------
// 8 lanes per node, float4 each (F=32)
__global__ void k_gather32(const int* __restrict__ row_ptr, const int* __restrict__ csr,
                           const float* __restrict__ hs2, const float* __restrict__ dinv,
                           const float* __restrict__ b2, const int* __restrict__ batch,
                           float* __restrict__ pooled, float* __restrict__ cnt, int N) {
    int t = blockIdx.x * blockDim.x + threadIdx.x;
    int v = t >> 3, q = t & 7;
    if (v >= N) return;
    const float4* hs4 = (const float4*)hs2;
    float4 sum = hs4[v * 8 + q];               // self-loop
    int beg = row_ptr[v], end = row_ptr[v + 1];
    for (int i = beg; i < end; ++i) {
        int s = csr[i];
        float4 a = hs4[s * 8 + q];
        sum.x += a.x; sum.y += a.y; sum.z += a.z; sum.w += a.w;
    }
    float d = dinv[v];
    float4 b = ((const float4*)b2)[q];
    float4 h;
    h.x = fmaxf(d * sum.x + b.x, 0.0f);
    h.y = fmaxf(d * sum.y + b.y, 0.0f);
    h.z = fmaxf(d * sum.z + b.z, 0.0f);
    h.w = fmaxf(d * sum.w + b.w, 0.0f);
    int g = batch[v];
    float* p = &pooled[g * 32 + q * 4];
    atomicAdd(p + 0, h.x);
    atomicAdd(p + 1, h.y);
    atomicAdd(p + 2, h.z);
    atomicAdd(p + 3, h.w);
    if (q == 0) atomicAdd(&cnt[g], 1.0f);
}

// ------- final linear head: out[g] = (pooled[g]/cnt[g]) @ Wl + bl -----------
__global__ void k_out(const float* __restrict__ pooled, const float* __restrict__ cnt,
                      const float* __restrict__ Wl, const float* __restrict__ bl,
                      float* __restrict__ out) {
    int t = blockIdx.x * blockDim.x + threadIdx.x;
    if (t >= NG * 3) return;
    int g = t / 3, c = t % 3;
    float inv = 1.0f / fmaxf(cnt[g], 1.0f);
    float s = bl[c];
#pragma unroll
    for (int f = 0; f < 32; ++f) s += pooled[g * 32 + f] * inv * Wl[f * 3 + c];
    out[g * 3 + c] = s;
}

extern "C" void kernel_launch(void* const* d_in, const int* in_sizes, int n_in,
                              void* d_out, int out_size, void* d_ws, size_t ws_size,
                              hipStream_t stream) {
    const float* x     = (const float*)d_in[0];
    const int*   ei    = (const int*)d_in[1];
    const int*   batch = (const int*)d_in[2];
    const float* W1    = (const float*)d_in[3];
    const float* b1    = (const float*)d_in[4];
    const float* W2    = (const float*)d_in[5];
    const float* b2    = (const float*)d_in[6];
    const float* Wl    = (const float*)d_in[7];
    const float* bl    = (const float*)d_in[8];

    const int N = in_sizes[0] / 3;
    const int E = in_sizes[1] / 2;
    const int* src = ei;
    const int* dst = ei + E;

    char* w = (char*)d_ws;
    int*   degi    = (int*)w;                 w += (size_t)N * 4;        // cursor later
    int*   row_ptr = (int*)w;                 w += (size_t)(N + 1) * 4;
    int*   part    = (int*)w;                 w += (size_t)SCAN_B * 4;
    int*   tmp     = (int*)w;                 w += (size_t)N * 4;
    float* dinv    = (float*)w;               w += (size_t)N * 4;
    int*   csr     = (int*)w;                 w += (size_t)E * 4;
    float* hs1     = (float*)w;               w += (size_t)N * 16 * 4;
    float* h1      = (float*)w;               w += (size_t)N * 16 * 4;
    float* hs2     = (float*)w;               w += (size_t)N * 32 * 4;
    float* pooled  = (float*)w;               w += (size_t)NG * 32 * 4;
    float* cnt     = (float*)w;               w += (size_t)NG * 4;

    const int B = 256;
    const int gN = (N + B - 1) / B;
    const int gE = (E + B - 1) / B;
    const int NB = (N + SCAN_B - 1) / SCAN_B;

    k_zero<<<gN, B, 0, stream>>>(degi, pooled, cnt, N);
    k_deg<<<gE, B, 0, stream>>>(dst, degi, E);
    k_scanA<<<NB, SCAN_B, 0, stream>>>(degi, tmp, part, N);
    k_scanB<<<1, SCAN_B, 0, stream>>>(part, NB);
    k_scanC<<<gN, B, 0, stream>>>(tmp, part, row_ptr, degi, dinv, N);
    k_fill<<<gE, B, 0, stream>>>(src, dst, row_ptr, degi, csr, E);
    k_l1node<<<gN, B, 0, stream>>>(x, W1, dinv, hs1, N);
    k_gather16<<<(N * 4 + B - 1) / B, B, 0, stream>>>(row_ptr, csr, hs1, dinv, b1, h1, N);
    k_mid2<<<gN, B, 0, stream>>>(h1, W2, dinv, hs2, N);
    k_gather32<<<(N * 8 + B - 1) / B, B, 0, stream>>>(row_ptr, csr, hs2, dinv, b2, batch,
                                                     pooled, cnt, N);
    k_out<<<(NG * 3 + B - 1) / B, B, 0, stream>>>(pooled, cnt, Wl, bl, (float*)d_out);
}